// Round 1
// baseline (237.827 us; speedup 1.0000x reference)
//
#include <hip/hip_runtime.h>
#include <cstdint>

#define BB   2
#define NN   16
#define TNN  8
#define BT   16
#define CC   64
#define VV   32
#define V3   (VV*VV*VV)
#define DD   48
#define HH   32
#define WW   32
#define FVL_ 0.86603

// ---------------------------------------------------------------------------
// Setup: per-view projection coefficients (double precision, 16 views).
// coord_i = depth*(A_i*w + B_i*h + C_i) + D_i  gives unnormalized voxel coords
// (align_corners=True mapping already folded in: coord = 31*xyz + 15.5).
// params[bt*16 + {0..11}] = A0,B0,C0,D0, A1,..., D2 ; [12]=near ; [13]=step
// ---------------------------------------------------------------------------
__global__ void setup_params(const float* __restrict__ RT, const float* __restrict__ Km,
                             const int* __restrict__ tidx, float* __restrict__ params) {
    int bt = threadIdx.x;
    if (bt >= BT) return;
    int b = bt / TNN, j = bt % TNN;
    int n = tidx[b * TNN + j];
    const float* pose = RT + (size_t)(b * NN + n) * 12;   // 3x4
    const float* K    = Km + (size_t)(b * NN + n) * 16;   // 4x4

    // cam_pos_i = -sum_j R[j][i]*T[j];  dist = |cam_pos|
    double T0 = pose[3], T1 = pose[7], T2 = pose[11];
    double cp0 = -((double)pose[0] * T0 + (double)pose[4] * T1 + (double)pose[8]  * T2);
    double cp1 = -((double)pose[1] * T0 + (double)pose[5] * T1 + (double)pose[9]  * T2);
    double cp2 = -((double)pose[2] * T0 + (double)pose[6] * T1 + (double)pose[10] * T2);
    double dist = sqrt(cp0*cp0 + cp1*cp1 + cp2*cp2);
    double nearv = dist - FVL_;
    double step  = 2.0 * FVL_ / (DD - 1);

    // A = K[:3,:3] @ pose_R (3x3), bv = K[:3,:3] @ pose_T
    double A[3][3], bv[3];
    #pragma unroll
    for (int i = 0; i < 3; ++i) {
        #pragma unroll
        for (int jj = 0; jj < 3; ++jj)
            A[i][jj] = (double)K[i*4+0]*pose[0*4+jj] + (double)K[i*4+1]*pose[1*4+jj]
                     + (double)K[i*4+2]*pose[2*4+jj];
        bv[i] = (double)K[i*4+0]*pose[3] + (double)K[i*4+1]*pose[7] + (double)K[i*4+2]*pose[11];
    }
    // Minv = inv(A) via adjugate
    double c00 =  A[1][1]*A[2][2] - A[1][2]*A[2][1];
    double c01 =  A[1][2]*A[2][0] - A[1][0]*A[2][2];
    double c02 =  A[1][0]*A[2][1] - A[1][1]*A[2][0];
    double det = A[0][0]*c00 + A[0][1]*c01 + A[0][2]*c02;
    double Mi[3][3];
    Mi[0][0] = c00 / det;
    Mi[0][1] = (A[0][2]*A[2][1] - A[0][1]*A[2][2]) / det;
    Mi[0][2] = (A[0][1]*A[1][2] - A[0][2]*A[1][1]) / det;
    Mi[1][0] = c01 / det;
    Mi[1][1] = (A[0][0]*A[2][2] - A[0][2]*A[2][0]) / det;
    Mi[1][2] = (A[0][2]*A[1][0] - A[0][0]*A[1][2]) / det;
    Mi[2][0] = c02 / det;
    Mi[2][1] = (A[0][1]*A[2][0] - A[0][0]*A[2][1]) / det;
    Mi[2][2] = (A[0][0]*A[1][1] - A[0][1]*A[1][0]) / det;
    double tv[3];
    #pragma unroll
    for (int i = 0; i < 3; ++i)
        tv[i] = -(Mi[i][0]*bv[0] + Mi[i][1]*bv[1] + Mi[i][2]*bv[2]);

    const double s = 31.0;  // 0.5*(V-1)/SVL
    float* p = params + bt * 16;
    #pragma unroll
    for (int i = 0; i < 3; ++i) {
        p[i*4+0] = (float)(s * Mi[i][0] * 8.0);
        p[i*4+1] = (float)(s * Mi[i][1] * 8.0);
        p[i*4+2] = (float)(s * Mi[i][2]);
        p[i*4+3] = (float)(s * tv[i] + 15.5);
    }
    p[12] = (float)nearv;
    p[13] = (float)step;
}

// ---------------------------------------------------------------------------
// Transpose (B,C,32,32,32) -> (B, 32*32*32, C) channel-last so that trilinear
// corner reads become coalesced float4 loads across channels.
// ---------------------------------------------------------------------------
__global__ __launch_bounds__(256) void transpose_vol(const float* __restrict__ vol,
                                                     float* __restrict__ volT) {
    int idx = blockIdx.x * 256 + threadIdx.x;   // B*C*V3 = 4194304 total
    int c    = idx & 63;
    int rest = idx >> 6;
    int zyx  = rest & (V3 - 1);
    int b    = rest >> 15;
    volT[(((size_t)b * V3 + zyx) << 6) | c] = vol[((size_t)(b * CC + c) * V3) + zyx];
}

// ---------------------------------------------------------------------------
// Main sampler. Block = (32 w-lanes) x (16 channel-quads) = 512 threads.
// One block per (bt,d,h). CHLAST=true reads the transposed volume (float4
// per corner); false is a fallback on the original layout (scalar gathers).
// ---------------------------------------------------------------------------
template<bool CHLAST>
__global__ __launch_bounds__(512) void sample_kernel(const float* __restrict__ vol,
                                                     const float* __restrict__ params,
                                                     float* __restrict__ feats,
                                                     float* __restrict__ depthv) {
    int w  = threadIdx.x;          // 0..31
    int ty = threadIdx.y;          // 0..15 -> channels 4*ty .. 4*ty+3
    int blk = blockIdx.x;          // bt*(DD*HH) + d*HH + h
    int h  = blk & 31;
    int t2 = blk >> 5;
    int d  = t2 % DD;
    int bt = t2 / DD;
    int b  = bt >> 3;              // TN = 8

    const float* p = params + bt * 16;
    float depth = fmaf(p[13], (float)d, p[12]);
    float fw = (float)w, fh = (float)h;
    float cx = fmaf(depth, fmaf(p[0], fw, fmaf(p[1], fh, p[2])),  p[3]);
    float cy = fmaf(depth, fmaf(p[4], fw, fmaf(p[5], fh, p[6])),  p[7]);
    float cz = fmaf(depth, fmaf(p[8], fw, fmaf(p[9], fh, p[10])), p[11]);

    float acc0 = 0.f, acc1 = 0.f, acc2 = 0.f, acc3 = 0.f;
    bool inside = (cx > -1.f) && (cx < 32.f) && (cy > -1.f) && (cy < 32.f)
               && (cz > -1.f) && (cz < 32.f);
    if (inside) {
        float xf = floorf(cx), yf = floorf(cy), zf = floorf(cz);
        int x0 = (int)xf, y0 = (int)yf, z0 = (int)zf;
        float xd = cx - xf, yd = cy - yf, zd = cz - zf;
        int x0c = max(x0, 0), x1c = min(x0 + 1, 31);
        int y0c = max(y0, 0), y1c = min(y0 + 1, 31);
        int z0c = max(z0, 0), z1c = min(z0 + 1, 31);
        float wx0 = (x0     >= 0) ? 1.f - xd : 0.f;
        float wx1 = (x0 + 1 <= 31) ? xd      : 0.f;
        float wy0 = (y0     >= 0) ? 1.f - yd : 0.f;
        float wy1 = (y0 + 1 <= 31) ? yd      : 0.f;
        float wz0 = (z0     >= 0) ? 1.f - zd : 0.f;
        float wz1 = (z0 + 1 <= 31) ? zd      : 0.f;

        if constexpr (CHLAST) {
            const size_t base = (size_t)b * ((size_t)V3 * 64) + (size_t)(ty << 2);
            #define CORNER(zc, yc, xc, WGT) do {                                         \
                const float4 v = *reinterpret_cast<const float4*>(                        \
                    vol + base + (((((size_t)(zc)) * 32 + (yc)) * 32 + (xc)) << 6));      \
                float wg = (WGT);                                                         \
                acc0 = fmaf(wg, v.x, acc0);  acc1 = fmaf(wg, v.y, acc1);                  \
                acc2 = fmaf(wg, v.z, acc2);  acc3 = fmaf(wg, v.w, acc3);                  \
            } while (0)
            CORNER(z0c, y0c, x0c, wz0 * wy0 * wx0);
            CORNER(z0c, y0c, x1c, wz0 * wy0 * wx1);
            CORNER(z0c, y1c, x0c, wz0 * wy1 * wx0);
            CORNER(z0c, y1c, x1c, wz0 * wy1 * wx1);
            CORNER(z1c, y0c, x0c, wz1 * wy0 * wx0);
            CORNER(z1c, y0c, x1c, wz1 * wy0 * wx1);
            CORNER(z1c, y1c, x0c, wz1 * wy1 * wx0);
            CORNER(z1c, y1c, x1c, wz1 * wy1 * wx1);
            #undef CORNER
        } else {
            int o000 = ((z0c * 32) + y0c) * 32 + x0c;
            int o001 = ((z0c * 32) + y0c) * 32 + x1c;
            int o010 = ((z0c * 32) + y1c) * 32 + x0c;
            int o011 = ((z0c * 32) + y1c) * 32 + x1c;
            int o100 = ((z1c * 32) + y0c) * 32 + x0c;
            int o101 = ((z1c * 32) + y0c) * 32 + x1c;
            int o110 = ((z1c * 32) + y1c) * 32 + x0c;
            int o111 = ((z1c * 32) + y1c) * 32 + x1c;
            float w000 = wz0*wy0*wx0, w001 = wz0*wy0*wx1, w010 = wz0*wy1*wx0, w011 = wz0*wy1*wx1;
            float w100 = wz1*wy0*wx0, w101 = wz1*wy0*wx1, w110 = wz1*wy1*wx0, w111 = wz1*wy1*wx1;
            float accs[4] = {0.f, 0.f, 0.f, 0.f};
            #pragma unroll
            for (int k = 0; k < 4; ++k) {
                const float* vc = vol + (size_t)(b * CC + (ty << 2) + k) * V3;
                float a = 0.f;
                a = fmaf(w000, vc[o000], a); a = fmaf(w001, vc[o001], a);
                a = fmaf(w010, vc[o010], a); a = fmaf(w011, vc[o011], a);
                a = fmaf(w100, vc[o100], a); a = fmaf(w101, vc[o101], a);
                a = fmaf(w110, vc[o110], a); a = fmaf(w111, vc[o111], a);
                accs[k] = a;
            }
            acc0 = accs[0]; acc1 = accs[1]; acc2 = accs[2]; acc3 = accs[3];
        }
    }

    const size_t CH = (size_t)DD * HH * WW;   // 49152
    size_t o = (((size_t)bt * CC + (ty << 2)) * DD + d) * (HH * WW) + h * WW + w;
    feats[o]          = acc0;
    feats[o + CH]     = acc1;
    feats[o + 2 * CH] = acc2;
    feats[o + 3 * CH] = acc3;
    if (ty == 0)
        depthv[((size_t)bt * DD + d) * (HH * WW) + h * WW + w] = depth;
}

extern "C" void kernel_launch(void* const* d_in, const int* in_sizes, int n_in,
                              void* d_out, int out_size, void* d_ws, size_t ws_size,
                              hipStream_t stream) {
    const float* vol  = (const float*)d_in[0];
    const float* RT   = (const float*)d_in[1];
    const float* Km   = (const float*)d_in[2];
    const int*   tidx = (const int*)d_in[3];

    float* feats  = (float*)d_out;
    float* depthv = feats + (size_t)BT * CC * DD * HH * WW;

    float* params = (float*)d_ws;
    float* volT   = (float*)((char*)d_ws + 4096);
    const size_t volT_bytes = (size_t)BB * CC * V3 * sizeof(float);
    bool use_cl = ws_size >= 4096 + volT_bytes;

    setup_params<<<1, 64, 0, stream>>>(RT, Km, tidx, params);
    if (use_cl) {
        transpose_vol<<<(BB * CC * V3) / 256, 256, 0, stream>>>(vol, volT);
        sample_kernel<true><<<BT * DD * HH, dim3(32, 16, 1), 0, stream>>>(volT, params, feats, depthv);
    } else {
        sample_kernel<false><<<BT * DD * HH, dim3(32, 16, 1), 0, stream>>>(vol, params, feats, depthv);
    }
}

// Round 3
// 220.846 us; speedup vs baseline: 1.0769x; 1.0769x over previous
//
#include <hip/hip_runtime.h>
#include <cstdint>

#define BB   2
#define NN   16
#define TNN  8
#define BT   16
#define CC   64
#define VV   32
#define V3   (VV*VV*VV)
#define DD   48
#define HH   32
#define WW   32
#define FVL_ 0.86603

// ---------------------------------------------------------------------------
// Setup: per-view projection coefficients (double precision, 16 views).
// coord_i = depth*(A_i*w + B_i*h + C_i) + D_i  gives unnormalized voxel coords
// (align_corners=True mapping already folded in: coord = 31*xyz + 15.5).
// ---------------------------------------------------------------------------
__global__ void setup_params(const float* __restrict__ RT, const float* __restrict__ Km,
                             const int* __restrict__ tidx, float* __restrict__ params) {
    int bt = threadIdx.x;
    if (bt >= BT) return;
    int b = bt / TNN, j = bt % TNN;
    int n = tidx[b * TNN + j];
    const float* pose = RT + (size_t)(b * NN + n) * 12;   // 3x4
    const float* K    = Km + (size_t)(b * NN + n) * 16;   // 4x4

    double T0 = pose[3], T1 = pose[7], T2 = pose[11];
    double cp0 = -((double)pose[0] * T0 + (double)pose[4] * T1 + (double)pose[8]  * T2);
    double cp1 = -((double)pose[1] * T0 + (double)pose[5] * T1 + (double)pose[9]  * T2);
    double cp2 = -((double)pose[2] * T0 + (double)pose[6] * T1 + (double)pose[10] * T2);
    double dist = sqrt(cp0*cp0 + cp1*cp1 + cp2*cp2);
    double nearv = dist - FVL_;
    double step  = 2.0 * FVL_ / (DD - 1);

    double A[3][3], bv[3];
    #pragma unroll
    for (int i = 0; i < 3; ++i) {
        #pragma unroll
        for (int jj = 0; jj < 3; ++jj)
            A[i][jj] = (double)K[i*4+0]*pose[0*4+jj] + (double)K[i*4+1]*pose[1*4+jj]
                     + (double)K[i*4+2]*pose[2*4+jj];
        bv[i] = (double)K[i*4+0]*pose[3] + (double)K[i*4+1]*pose[7] + (double)K[i*4+2]*pose[11];
    }
    double c00 =  A[1][1]*A[2][2] - A[1][2]*A[2][1];
    double c01 =  A[1][2]*A[2][0] - A[1][0]*A[2][2];
    double c02 =  A[1][0]*A[2][1] - A[1][1]*A[2][0];
    double det = A[0][0]*c00 + A[0][1]*c01 + A[0][2]*c02;
    double Mi[3][3];
    Mi[0][0] = c00 / det;
    Mi[0][1] = (A[0][2]*A[2][1] - A[0][1]*A[2][2]) / det;
    Mi[0][2] = (A[0][1]*A[1][2] - A[0][2]*A[1][1]) / det;
    Mi[1][0] = c01 / det;
    Mi[1][1] = (A[0][0]*A[2][2] - A[0][2]*A[2][0]) / det;
    Mi[1][2] = (A[0][2]*A[1][0] - A[0][0]*A[1][2]) / det;
    Mi[2][0] = c02 / det;
    Mi[2][1] = (A[0][1]*A[2][0] - A[0][0]*A[2][1]) / det;
    Mi[2][2] = (A[0][0]*A[1][1] - A[0][1]*A[1][0]) / det;
    double tv[3];
    #pragma unroll
    for (int i = 0; i < 3; ++i)
        tv[i] = -(Mi[i][0]*bv[0] + Mi[i][1]*bv[1] + Mi[i][2]*bv[2]);

    const double s = 31.0;  // 0.5*(V-1)/SVL
    float* p = params + bt * 16;
    #pragma unroll
    for (int i = 0; i < 3; ++i) {
        p[i*4+0] = (float)(s * Mi[i][0] * 8.0);
        p[i*4+1] = (float)(s * Mi[i][1] * 8.0);
        p[i*4+2] = (float)(s * Mi[i][2]);
        p[i*4+3] = (float)(s * tv[i] + 15.5);
    }
    p[12] = (float)nearv;
    p[13] = (float)step;
}

// ---------------------------------------------------------------------------
// LDS-tiled transpose: (B,C,32^3) -> (B, 32^3, C). Both sides coalesced.
// Grid: B * (V3/64) blocks of 256 threads; tile = 64 zyx x 64 c.
// ---------------------------------------------------------------------------
__global__ __launch_bounds__(256) void transpose_vol2(const float* __restrict__ vol,
                                                      float* __restrict__ volT) {
    __shared__ float tl[64 * 65];
    int b    = blockIdx.x >> 9;          // V3/64 = 512 tiles per batch
    int tile = blockIdx.x & 511;
    size_t zyx0 = (size_t)tile << 6;
    int l  = threadIdx.x & 63;
    int gq = threadIdx.x >> 6;           // 0..3
    #pragma unroll
    for (int k = 0; k < 16; ++k) {
        int c = (gq << 4) + k;
        tl[l * 65 + c] = vol[(((size_t)(b * 64 + c)) << 15) + zyx0 + l];
    }
    __syncthreads();
    #pragma unroll
    for (int k = 0; k < 16; ++k) {
        int zy = (gq << 4) + k;
        volT[((size_t)b << 21) + ((zyx0 + zy) << 6) + l] = tl[zy * 65 + l];
    }
}

// ---------------------------------------------------------------------------
// Main sampler on channel-last volume.
// Block = 512 threads (8 waves) per (bt,d,h) row of 32 w-points.
// Wave lane = point*16 + channel_quad: each corner load instruction reads
// 4 x 256B fully-contiguous channel records (float4/lane). Accumulators go
// through an LDS [32 w][64 c] tile so the global write phase is w-fastest
// coalesced into the (BT,C,D,H,W) output.
// ---------------------------------------------------------------------------
__global__ __launch_bounds__(512) void sample_cl2(const float* __restrict__ volT,
                                                  const float* __restrict__ params,
                                                  float* __restrict__ feats,
                                                  float* __restrict__ depthv) {
    __shared__ float lds[32 * 68];
    int t   = threadIdx.x;
    int blk = blockIdx.x;                // bt*(DD*HH) + d*HH + h
    int h  = blk & 31;
    int t2 = blk >> 5;
    int d  = t2 % DD;
    int bt = t2 / DD;
    int b  = bt >> 3;                    // TN = 8

    const float* p = params + bt * 16;
    float depth = fmaf(p[13], (float)d, p[12]);

    int lane = t & 63;
    int wv   = t >> 6;                   // 0..7
    int pp   = lane >> 4;                // 0..3 point within wave
    int q    = lane & 15;                // channel quad
    int w    = (wv << 2) | pp;           // 0..31

    float fw = (float)w, fh = (float)h;
    float cx = fmaf(depth, fmaf(p[0], fw, fmaf(p[1], fh, p[2])),  p[3]);
    float cy = fmaf(depth, fmaf(p[4], fw, fmaf(p[5], fh, p[6])),  p[7]);
    float cz = fmaf(depth, fmaf(p[8], fw, fmaf(p[9], fh, p[10])), p[11]);

    float acc0 = 0.f, acc1 = 0.f, acc2 = 0.f, acc3 = 0.f;
    bool inside = (cx > -1.f) && (cx < 32.f) && (cy > -1.f) && (cy < 32.f)
               && (cz > -1.f) && (cz < 32.f);
    if (inside) {
        float xf = floorf(cx), yf = floorf(cy), zf = floorf(cz);
        int x0 = (int)xf, y0 = (int)yf, z0 = (int)zf;
        float xd = cx - xf, yd = cy - yf, zd = cz - zf;
        int x0c = max(x0, 0), x1c = min(x0 + 1, 31);
        int y0c = max(y0, 0), y1c = min(y0 + 1, 31);
        int z0c = max(z0, 0), z1c = min(z0 + 1, 31);
        float wx0 = (x0     >= 0)  ? 1.f - xd : 0.f;
        float wx1 = (x0 + 1 <= 31) ? xd       : 0.f;
        float wy0 = (y0     >= 0)  ? 1.f - yd : 0.f;
        float wy1 = (y0 + 1 <= 31) ? yd       : 0.f;
        float wz0 = (z0     >= 0)  ? 1.f - zd : 0.f;
        float wz1 = (z0 + 1 <= 31) ? zd       : 0.f;

        const float* vb = volT + (((size_t)b << 21)) + (q << 2);
        #define CORNER(zc, yc, xc, WGT) do {                                        \
            const float4 v = *reinterpret_cast<const float4*>(                       \
                vb + ((((size_t)(zc) * 32 + (yc)) * 32 + (xc)) << 6));               \
            float wg = (WGT);                                                        \
            acc0 = fmaf(wg, v.x, acc0);  acc1 = fmaf(wg, v.y, acc1);                 \
            acc2 = fmaf(wg, v.z, acc2);  acc3 = fmaf(wg, v.w, acc3);                 \
        } while (0)
        CORNER(z0c, y0c, x0c, wz0 * wy0 * wx0);
        CORNER(z0c, y0c, x1c, wz0 * wy0 * wx1);
        CORNER(z0c, y1c, x0c, wz0 * wy1 * wx0);
        CORNER(z0c, y1c, x1c, wz0 * wy1 * wx1);
        CORNER(z1c, y0c, x0c, wz1 * wy0 * wx0);
        CORNER(z1c, y0c, x1c, wz1 * wy0 * wx1);
        CORNER(z1c, y1c, x0c, wz1 * wy1 * wx0);
        CORNER(z1c, y1c, x1c, wz1 * wy1 * wx1);
        #undef CORNER
    }

    // stage [w][c] tile (pad 68 floats/row; 16B-aligned float4 slots)
    float4 av = {acc0, acc1, acc2, acc3};
    *reinterpret_cast<float4*>(&lds[w * 68 + (q << 2)]) = av;
    __syncthreads();

    // transposed coalesced write: thread -> (w2, channel quad g)
    int w2 = t & 31;
    int g  = t >> 5;                     // 0..15
    float4 rv = *reinterpret_cast<const float4*>(&lds[w2 * 68 + (g << 2)]);
    const size_t CHs = (size_t)DD * HH * WW;
    size_t o = (((size_t)(bt * CC + (g << 2)) * DD + d) * (HH * WW)) + h * WW + w2;
    feats[o]           = rv.x;
    feats[o + CHs]     = rv.y;
    feats[o + 2 * CHs] = rv.z;
    feats[o + 3 * CHs] = rv.w;
    if (t < 32)
        depthv[((size_t)bt * DD + d) * (HH * WW) + h * WW + t] = depth;
}

// ---------------------------------------------------------------------------
// Fallback on original layout (only if workspace too small for volT).
// ---------------------------------------------------------------------------
__global__ __launch_bounds__(512) void sample_fallback(const float* __restrict__ vol,
                                                       const float* __restrict__ params,
                                                       float* __restrict__ feats,
                                                       float* __restrict__ depthv) {
    int w  = threadIdx.x;
    int ty = threadIdx.y;
    int blk = blockIdx.x;
    int h  = blk & 31;
    int t2 = blk >> 5;
    int d  = t2 % DD;
    int bt = t2 / DD;
    int b  = bt >> 3;

    const float* p = params + bt * 16;
    float depth = fmaf(p[13], (float)d, p[12]);
    float fw = (float)w, fh = (float)h;
    float cx = fmaf(depth, fmaf(p[0], fw, fmaf(p[1], fh, p[2])),  p[3]);
    float cy = fmaf(depth, fmaf(p[4], fw, fmaf(p[5], fh, p[6])),  p[7]);
    float cz = fmaf(depth, fmaf(p[8], fw, fmaf(p[9], fh, p[10])), p[11]);

    float accs[4] = {0.f, 0.f, 0.f, 0.f};
    bool inside = (cx > -1.f) && (cx < 32.f) && (cy > -1.f) && (cy < 32.f)
               && (cz > -1.f) && (cz < 32.f);
    if (inside) {
        float xf = floorf(cx), yf = floorf(cy), zf = floorf(cz);
        int x0 = (int)xf, y0 = (int)yf, z0 = (int)zf;
        float xd = cx - xf, yd = cy - yf, zd = cz - zf;
        int x0c = max(x0, 0), x1c = min(x0 + 1, 31);
        int y0c = max(y0, 0), y1c = min(y0 + 1, 31);
        int z0c = max(z0, 0), z1c = min(z0 + 1, 31);
        float wx0 = (x0     >= 0)  ? 1.f - xd : 0.f;
        float wx1 = (x0 + 1 <= 31) ? xd       : 0.f;
        float wy0 = (y0     >= 0)  ? 1.f - yd : 0.f;
        float wy1 = (y0 + 1 <= 31) ? yd       : 0.f;
        float wz0 = (z0     >= 0)  ? 1.f - zd : 0.f;
        float wz1 = (z0 + 1 <= 31) ? zd       : 0.f;
        int o000 = ((z0c * 32) + y0c) * 32 + x0c;
        int o001 = ((z0c * 32) + y0c) * 32 + x1c;
        int o010 = ((z0c * 32) + y1c) * 32 + x0c;
        int o011 = ((z0c * 32) + y1c) * 32 + x1c;
        int o100 = ((z1c * 32) + y0c) * 32 + x0c;
        int o101 = ((z1c * 32) + y0c) * 32 + x1c;
        int o110 = ((z1c * 32) + y1c) * 32 + x0c;
        int o111 = ((z1c * 32) + y1c) * 32 + x1c;
        float w000 = wz0*wy0*wx0, w001 = wz0*wy0*wx1, w010 = wz0*wy1*wx0, w011 = wz0*wy1*wx1;
        float w100 = wz1*wy0*wx0, w101 = wz1*wy0*wx1, w110 = wz1*wy1*wx0, w111 = wz1*wy1*wx1;
        #pragma unroll
        for (int k = 0; k < 4; ++k) {
            const float* vc = vol + (size_t)(b * CC + (ty << 2) + k) * V3;
            float a = 0.f;
            a = fmaf(w000, vc[o000], a); a = fmaf(w001, vc[o001], a);
            a = fmaf(w010, vc[o010], a); a = fmaf(w011, vc[o011], a);
            a = fmaf(w100, vc[o100], a); a = fmaf(w101, vc[o101], a);
            a = fmaf(w110, vc[o110], a); a = fmaf(w111, vc[o111], a);
            accs[k] = a;
        }
    }
    const size_t CHs = (size_t)DD * HH * WW;
    size_t o = (((size_t)bt * CC + (ty << 2)) * DD + d) * (HH * WW) + h * WW + w;
    feats[o]           = accs[0];
    feats[o + CHs]     = accs[1];
    feats[o + 2 * CHs] = accs[2];
    feats[o + 3 * CHs] = accs[3];
    if (ty == 0)
        depthv[((size_t)bt * DD + d) * (HH * WW) + h * WW + w] = depth;
}

extern "C" void kernel_launch(void* const* d_in, const int* in_sizes, int n_in,
                              void* d_out, int out_size, void* d_ws, size_t ws_size,
                              hipStream_t stream) {
    const float* vol  = (const float*)d_in[0];
    const float* RT   = (const float*)d_in[1];
    const float* Km   = (const float*)d_in[2];
    const int*   tidx = (const int*)d_in[3];

    float* feats  = (float*)d_out;
    float* depthv = feats + (size_t)BT * CC * DD * HH * WW;

    float* params = (float*)d_ws;
    float* volT   = (float*)((char*)d_ws + 4096);
    const size_t volT_bytes = (size_t)BB * CC * V3 * sizeof(float);
    bool use_cl = ws_size >= 4096 + volT_bytes;

    setup_params<<<1, 64, 0, stream>>>(RT, Km, tidx, params);
    if (use_cl) {
        transpose_vol2<<<BB * (V3 / 64), 256, 0, stream>>>(vol, volT);
        sample_cl2<<<BT * DD * HH, 512, 0, stream>>>(volT, params, feats, depthv);
    } else {
        sample_fallback<<<BT * DD * HH, dim3(32, 16, 1), 0, stream>>>(vol, params, feats, depthv);
    }
}

// Round 4
// 218.514 us; speedup vs baseline: 1.0884x; 1.0107x over previous
//
#include <hip/hip_runtime.h>
#include <cstdint>

#define BB   2
#define NN   16
#define TNN  8
#define BT   16
#define CC   64
#define VV   32
#define V3   (VV*VV*VV)
#define DD   48
#define HH   32
#define WW   32
#define FVL_ 0.86603

// ---------------------------------------------------------------------------
// Setup: per-view projection coefficients (double precision, 16 views).
// coord_i = depth*(A_i*w + B_i*h + C_i) + D_i  gives unnormalized voxel coords
// (align_corners=True mapping folded in: coord = 31*xyz + 15.5).
// ---------------------------------------------------------------------------
__global__ void setup_params(const float* __restrict__ RT, const float* __restrict__ Km,
                             const int* __restrict__ tidx, float* __restrict__ params) {
    int bt = threadIdx.x;
    if (bt >= BT) return;
    int b = bt / TNN, j = bt % TNN;
    int n = tidx[b * TNN + j];
    const float* pose = RT + (size_t)(b * NN + n) * 12;   // 3x4
    const float* K    = Km + (size_t)(b * NN + n) * 16;   // 4x4

    double T0 = pose[3], T1 = pose[7], T2 = pose[11];
    double cp0 = -((double)pose[0] * T0 + (double)pose[4] * T1 + (double)pose[8]  * T2);
    double cp1 = -((double)pose[1] * T0 + (double)pose[5] * T1 + (double)pose[9]  * T2);
    double cp2 = -((double)pose[2] * T0 + (double)pose[6] * T1 + (double)pose[10] * T2);
    double dist = sqrt(cp0*cp0 + cp1*cp1 + cp2*cp2);
    double nearv = dist - FVL_;
    double step  = 2.0 * FVL_ / (DD - 1);

    double A[3][3], bv[3];
    #pragma unroll
    for (int i = 0; i < 3; ++i) {
        #pragma unroll
        for (int jj = 0; jj < 3; ++jj)
            A[i][jj] = (double)K[i*4+0]*pose[0*4+jj] + (double)K[i*4+1]*pose[1*4+jj]
                     + (double)K[i*4+2]*pose[2*4+jj];
        bv[i] = (double)K[i*4+0]*pose[3] + (double)K[i*4+1]*pose[7] + (double)K[i*4+2]*pose[11];
    }
    double c00 =  A[1][1]*A[2][2] - A[1][2]*A[2][1];
    double c01 =  A[1][2]*A[2][0] - A[1][0]*A[2][2];
    double c02 =  A[1][0]*A[2][1] - A[1][1]*A[2][0];
    double det = A[0][0]*c00 + A[0][1]*c01 + A[0][2]*c02;
    double Mi[3][3];
    Mi[0][0] = c00 / det;
    Mi[0][1] = (A[0][2]*A[2][1] - A[0][1]*A[2][2]) / det;
    Mi[0][2] = (A[0][1]*A[1][2] - A[0][2]*A[1][1]) / det;
    Mi[1][0] = c01 / det;
    Mi[1][1] = (A[0][0]*A[2][2] - A[0][2]*A[2][0]) / det;
    Mi[1][2] = (A[0][2]*A[1][0] - A[0][0]*A[1][2]) / det;
    Mi[2][0] = c02 / det;
    Mi[2][1] = (A[0][1]*A[2][0] - A[0][0]*A[2][1]) / det;
    Mi[2][2] = (A[0][0]*A[1][1] - A[0][1]*A[1][0]) / det;
    double tv[3];
    #pragma unroll
    for (int i = 0; i < 3; ++i)
        tv[i] = -(Mi[i][0]*bv[0] + Mi[i][1]*bv[1] + Mi[i][2]*bv[2]);

    const double s = 31.0;  // 0.5*(V-1)/SVL
    float* p = params + bt * 16;
    #pragma unroll
    for (int i = 0; i < 3; ++i) {
        p[i*4+0] = (float)(s * Mi[i][0] * 8.0);
        p[i*4+1] = (float)(s * Mi[i][1] * 8.0);
        p[i*4+2] = (float)(s * Mi[i][2]);
        p[i*4+3] = (float)(s * tv[i] + 15.5);
    }
    p[12] = (float)nearv;
    p[13] = (float)step;
}

// ---------------------------------------------------------------------------
// Convert + transpose: (B,C,32^3) f32 -> (B, 32^3, C) bf16 (RNE).
// LDS-tiled, both global sides coalesced. Grid: B*512 blocks x 256 threads.
// ---------------------------------------------------------------------------
__global__ __launch_bounds__(256) void convert_transpose(const float* __restrict__ vol,
                                                         ushort* __restrict__ volTb) {
    __shared__ ushort tl[64 * 66];     // stride 66 (even) -> conflict-free
    int b    = blockIdx.x >> 9;        // 512 tiles per batch
    int tile = blockIdx.x & 511;
    size_t zyx0 = (size_t)tile << 6;
    int l  = threadIdx.x & 63;
    int gq = threadIdx.x >> 6;         // 0..3
    #pragma unroll
    for (int k = 0; k < 16; ++k) {
        int c = (gq << 4) + k;
        float v = vol[(((size_t)(b * 64 + c)) << 15) + zyx0 + l];
        uint32_t u = __float_as_uint(v);
        tl[l * 66 + c] = (ushort)((u + 0x7fffu + ((u >> 16) & 1u)) >> 16);  // RNE
    }
    __syncthreads();
    #pragma unroll
    for (int k = 0; k < 16; ++k) {
        int zy = (gq << 4) + k;
        volTb[((size_t)b << 21) + ((zyx0 + zy) << 6) + l] = tl[zy * 66 + l];
    }
}

// ---------------------------------------------------------------------------
// Main sampler on bf16 channel-last volume.
// Block = 512 threads (8 waves) covering 64 sample points (2 h-rows).
// Wave lane = point*8 + octet: corner load = uint4 (8 bf16 channels, 16B);
// 8 lanes x 16B = one dense 128B record; 8 points/wave -> 1KB per load instr.
// f32 accumulate; LDS [64 pt][65 c] transpose for coalesced channel-major
// output stores (256B per wave-instr).
// ---------------------------------------------------------------------------
__global__ __launch_bounds__(512) void sample_bf16(const ushort* __restrict__ volTb,
                                                   const float* __restrict__ params,
                                                   float* __restrict__ feats,
                                                   float* __restrict__ depthv) {
    __shared__ float lds[64 * 65];
    int t   = threadIdx.x;
    int blk = blockIdx.x;              // bt*(DD*16) + d*16 + hp
    int hp = blk & 15;
    int t2 = blk >> 4;
    int d  = t2 % DD;
    int bt = t2 / DD;
    int b  = bt >> 3;                  // TN = 8

    const float* p = params + bt * 16;
    float depth = fmaf(p[13], (float)d, p[12]);

    int lane = t & 63;
    int wv   = t >> 6;                 // 0..7
    int pp   = lane >> 3;              // 0..7 point within wave
    int q    = lane & 7;               // channel octet
    int pidx = (wv << 3) | pp;         // 0..63
    int w    = pidx & 31;
    int h    = (hp << 1) | (pidx >> 5);

    float fw = (float)w, fh = (float)h;
    float cx = fmaf(depth, fmaf(p[0], fw, fmaf(p[1], fh, p[2])),  p[3]);
    float cy = fmaf(depth, fmaf(p[4], fw, fmaf(p[5], fh, p[6])),  p[7]);
    float cz = fmaf(depth, fmaf(p[8], fw, fmaf(p[9], fh, p[10])), p[11]);

    float acc[8] = {0.f, 0.f, 0.f, 0.f, 0.f, 0.f, 0.f, 0.f};
    bool inside = (cx > -1.f) && (cx < 32.f) && (cy > -1.f) && (cy < 32.f)
               && (cz > -1.f) && (cz < 32.f);
    if (inside) {
        float xf = floorf(cx), yf = floorf(cy), zf = floorf(cz);
        int x0 = (int)xf, y0 = (int)yf, z0 = (int)zf;
        float xd = cx - xf, yd = cy - yf, zd = cz - zf;
        int x0c = max(x0, 0), x1c = min(x0 + 1, 31);
        int y0c = max(y0, 0), y1c = min(y0 + 1, 31);
        int z0c = max(z0, 0), z1c = min(z0 + 1, 31);
        float wx0 = (x0     >= 0)  ? 1.f - xd : 0.f;
        float wx1 = (x0 + 1 <= 31) ? xd       : 0.f;
        float wy0 = (y0     >= 0)  ? 1.f - yd : 0.f;
        float wy1 = (y0 + 1 <= 31) ? yd       : 0.f;
        float wz0 = (z0     >= 0)  ? 1.f - zd : 0.f;
        float wz1 = (z0 + 1 <= 31) ? zd       : 0.f;

        const ushort* vb = volTb + ((size_t)b << 21) + (q << 3);
        #define CORNER(zc, yc, xc, WGT) do {                                         \
            const uint4 v = *reinterpret_cast<const uint4*>(                          \
                vb + ((((size_t)(zc) * 32 + (yc)) * 32 + (xc)) << 6));                \
            float wg = (WGT);                                                         \
            acc[0] = fmaf(wg, __uint_as_float(v.x << 16),          acc[0]);           \
            acc[1] = fmaf(wg, __uint_as_float(v.x & 0xffff0000u),  acc[1]);           \
            acc[2] = fmaf(wg, __uint_as_float(v.y << 16),          acc[2]);           \
            acc[3] = fmaf(wg, __uint_as_float(v.y & 0xffff0000u),  acc[3]);           \
            acc[4] = fmaf(wg, __uint_as_float(v.z << 16),          acc[4]);           \
            acc[5] = fmaf(wg, __uint_as_float(v.z & 0xffff0000u),  acc[5]);           \
            acc[6] = fmaf(wg, __uint_as_float(v.w << 16),          acc[6]);           \
            acc[7] = fmaf(wg, __uint_as_float(v.w & 0xffff0000u),  acc[7]);           \
        } while (0)
        CORNER(z0c, y0c, x0c, wz0 * wy0 * wx0);
        CORNER(z0c, y0c, x1c, wz0 * wy0 * wx1);
        CORNER(z0c, y1c, x0c, wz0 * wy1 * wx0);
        CORNER(z0c, y1c, x1c, wz0 * wy1 * wx1);
        CORNER(z1c, y0c, x0c, wz1 * wy0 * wx0);
        CORNER(z1c, y0c, x1c, wz1 * wy0 * wx1);
        CORNER(z1c, y1c, x0c, wz1 * wy1 * wx0);
        CORNER(z1c, y1c, x1c, wz1 * wy1 * wx1);
        #undef CORNER
    }

    // stage [pt][c]: pad 65 -> write banks (65*pt + c) % 32 = 2-way (free)
    #pragma unroll
    for (int j = 0; j < 8; ++j)
        lds[pidx * 65 + (q << 3) + j] = acc[j];
    __syncthreads();

    // coalesced channel-major write: per wave, c uniform, lanes vary pt
    int pt = t & 63;
    int c8 = t >> 6;                   // wave index 0..7
    int h0 = hp << 1;
    #pragma unroll
    for (int j = 0; j < 8; ++j) {
        int c = (c8 << 3) + j;
        size_t o = (((size_t)(bt * CC + c) * DD + d) << 10) + (h0 << 5) + pt;
        feats[o] = lds[pt * 65 + c];
    }
    if (t < 64)
        depthv[(((size_t)bt * DD + d) << 10) + (h0 << 5) + t] = depth;
}

// ---------------------------------------------------------------------------
// Fallback on original layout (only if workspace too small for volTb).
// ---------------------------------------------------------------------------
__global__ __launch_bounds__(512) void sample_fallback(const float* __restrict__ vol,
                                                       const float* __restrict__ params,
                                                       float* __restrict__ feats,
                                                       float* __restrict__ depthv) {
    int w  = threadIdx.x;
    int ty = threadIdx.y;
    int blk = blockIdx.x;
    int h  = blk & 31;
    int t2 = blk >> 5;
    int d  = t2 % DD;
    int bt = t2 / DD;
    int b  = bt >> 3;

    const float* p = params + bt * 16;
    float depth = fmaf(p[13], (float)d, p[12]);
    float fw = (float)w, fh = (float)h;
    float cx = fmaf(depth, fmaf(p[0], fw, fmaf(p[1], fh, p[2])),  p[3]);
    float cy = fmaf(depth, fmaf(p[4], fw, fmaf(p[5], fh, p[6])),  p[7]);
    float cz = fmaf(depth, fmaf(p[8], fw, fmaf(p[9], fh, p[10])), p[11]);

    float accs[4] = {0.f, 0.f, 0.f, 0.f};
    bool inside = (cx > -1.f) && (cx < 32.f) && (cy > -1.f) && (cy < 32.f)
               && (cz > -1.f) && (cz < 32.f);
    if (inside) {
        float xf = floorf(cx), yf = floorf(cy), zf = floorf(cz);
        int x0 = (int)xf, y0 = (int)yf, z0 = (int)zf;
        float xd = cx - xf, yd = cy - yf, zd = cz - zf;
        int x0c = max(x0, 0), x1c = min(x0 + 1, 31);
        int y0c = max(y0, 0), y1c = min(y0 + 1, 31);
        int z0c = max(z0, 0), z1c = min(z0 + 1, 31);
        float wx0 = (x0     >= 0)  ? 1.f - xd : 0.f;
        float wx1 = (x0 + 1 <= 31) ? xd       : 0.f;
        float wy0 = (y0     >= 0)  ? 1.f - yd : 0.f;
        float wy1 = (y0 + 1 <= 31) ? yd       : 0.f;
        float wz0 = (z0     >= 0)  ? 1.f - zd : 0.f;
        float wz1 = (z0 + 1 <= 31) ? zd       : 0.f;
        int o000 = ((z0c * 32) + y0c) * 32 + x0c;
        int o001 = ((z0c * 32) + y0c) * 32 + x1c;
        int o010 = ((z0c * 32) + y1c) * 32 + x0c;
        int o011 = ((z0c * 32) + y1c) * 32 + x1c;
        int o100 = ((z1c * 32) + y0c) * 32 + x0c;
        int o101 = ((z1c * 32) + y0c) * 32 + x1c;
        int o110 = ((z1c * 32) + y1c) * 32 + x0c;
        int o111 = ((z1c * 32) + y1c) * 32 + x1c;
        float w000 = wz0*wy0*wx0, w001 = wz0*wy0*wx1, w010 = wz0*wy1*wx0, w011 = wz0*wy1*wx1;
        float w100 = wz1*wy0*wx0, w101 = wz1*wy0*wx1, w110 = wz1*wy1*wx0, w111 = wz1*wy1*wx1;
        #pragma unroll
        for (int k = 0; k < 4; ++k) {
            const float* vc = vol + (size_t)(b * CC + (ty << 2) + k) * V3;
            float a = 0.f;
            a = fmaf(w000, vc[o000], a); a = fmaf(w001, vc[o001], a);
            a = fmaf(w010, vc[o010], a); a = fmaf(w011, vc[o011], a);
            a = fmaf(w100, vc[o100], a); a = fmaf(w101, vc[o101], a);
            a = fmaf(w110, vc[o110], a); a = fmaf(w111, vc[o111], a);
            accs[k] = a;
        }
    }
    const size_t CHs = (size_t)DD * HH * WW;
    size_t o = (((size_t)bt * CC + (ty << 2)) * DD + d) * (HH * WW) + h * WW + w;
    feats[o]           = accs[0];
    feats[o + CHs]     = accs[1];
    feats[o + 2 * CHs] = accs[2];
    feats[o + 3 * CHs] = accs[3];
    if (ty == 0)
        depthv[((size_t)bt * DD + d) * (HH * WW) + h * WW + w] = depth;
}

extern "C" void kernel_launch(void* const* d_in, const int* in_sizes, int n_in,
                              void* d_out, int out_size, void* d_ws, size_t ws_size,
                              hipStream_t stream) {
    const float* vol  = (const float*)d_in[0];
    const float* RT   = (const float*)d_in[1];
    const float* Km   = (const float*)d_in[2];
    const int*   tidx = (const int*)d_in[3];

    float* feats  = (float*)d_out;
    float* depthv = feats + (size_t)BT * CC * DD * HH * WW;

    float*  params = (float*)d_ws;
    ushort* volTb  = (ushort*)((char*)d_ws + 4096);
    const size_t volTb_bytes = (size_t)BB * CC * V3 * sizeof(ushort);   // 8 MB
    bool use_cl = ws_size >= 4096 + volTb_bytes;

    setup_params<<<1, 64, 0, stream>>>(RT, Km, tidx, params);
    if (use_cl) {
        convert_transpose<<<BB * (V3 / 64), 256, 0, stream>>>(vol, volTb);
        sample_bf16<<<BT * DD * (HH / 2), 512, 0, stream>>>(volTb, params, feats, depthv);
    } else {
        sample_fallback<<<BT * DD * HH, dim3(32, 16, 1), 0, stream>>>(vol, params, feats, depthv);
    }
}

// Round 5
// 214.597 us; speedup vs baseline: 1.1082x; 1.0183x over previous
//
#include <hip/hip_runtime.h>
#include <cstdint>

#define BB   2
#define NN   16
#define TNN  8
#define BT   16
#define CC   64
#define VV   32
#define V3   (VV*VV*VV)
#define DD   48
#define HH   32
#define WW   32
#define FVL_ 0.86603

// ---------------------------------------------------------------------------
// Per-view projection coefficients (double precision).
// coord_i = depth*(A_i*w + B_i*h + C_i) + D_i  (align_corners mapping folded:
// coord = 31*xyz + 15.5).  params[bt*16+{0..11}] = rows; [12]=near; [13]=step
// ---------------------------------------------------------------------------
__device__ void setup_one(int bt, const float* __restrict__ RT,
                          const float* __restrict__ Km,
                          const int* __restrict__ tidx, float* __restrict__ params) {
    int b = bt / TNN, j = bt % TNN;
    int n = tidx[b * TNN + j];
    const float* pose = RT + (size_t)(b * NN + n) * 12;   // 3x4
    const float* K    = Km + (size_t)(b * NN + n) * 16;   // 4x4

    double T0 = pose[3], T1 = pose[7], T2 = pose[11];
    double cp0 = -((double)pose[0] * T0 + (double)pose[4] * T1 + (double)pose[8]  * T2);
    double cp1 = -((double)pose[1] * T0 + (double)pose[5] * T1 + (double)pose[9]  * T2);
    double cp2 = -((double)pose[2] * T0 + (double)pose[6] * T1 + (double)pose[10] * T2);
    double dist = sqrt(cp0*cp0 + cp1*cp1 + cp2*cp2);
    double nearv = dist - FVL_;
    double step  = 2.0 * FVL_ / (DD - 1);

    double A[3][3], bv[3];
    #pragma unroll
    for (int i = 0; i < 3; ++i) {
        #pragma unroll
        for (int jj = 0; jj < 3; ++jj)
            A[i][jj] = (double)K[i*4+0]*pose[0*4+jj] + (double)K[i*4+1]*pose[1*4+jj]
                     + (double)K[i*4+2]*pose[2*4+jj];
        bv[i] = (double)K[i*4+0]*pose[3] + (double)K[i*4+1]*pose[7] + (double)K[i*4+2]*pose[11];
    }
    double c00 =  A[1][1]*A[2][2] - A[1][2]*A[2][1];
    double c01 =  A[1][2]*A[2][0] - A[1][0]*A[2][2];
    double c02 =  A[1][0]*A[2][1] - A[1][1]*A[2][0];
    double det = A[0][0]*c00 + A[0][1]*c01 + A[0][2]*c02;
    double Mi[3][3];
    Mi[0][0] = c00 / det;
    Mi[0][1] = (A[0][2]*A[2][1] - A[0][1]*A[2][2]) / det;
    Mi[0][2] = (A[0][1]*A[1][2] - A[0][2]*A[1][1]) / det;
    Mi[1][0] = c01 / det;
    Mi[1][1] = (A[0][0]*A[2][2] - A[0][2]*A[2][0]) / det;
    Mi[1][2] = (A[0][2]*A[1][0] - A[0][0]*A[1][2]) / det;
    Mi[2][0] = c02 / det;
    Mi[2][1] = (A[0][1]*A[2][0] - A[0][0]*A[2][1]) / det;
    Mi[2][2] = (A[0][0]*A[1][1] - A[0][1]*A[1][0]) / det;
    double tv[3];
    #pragma unroll
    for (int i = 0; i < 3; ++i)
        tv[i] = -(Mi[i][0]*bv[0] + Mi[i][1]*bv[1] + Mi[i][2]*bv[2]);

    const double s = 31.0;  // 0.5*(V-1)/SVL
    float* p = params + bt * 16;
    #pragma unroll
    for (int i = 0; i < 3; ++i) {
        p[i*4+0] = (float)(s * Mi[i][0] * 8.0);
        p[i*4+1] = (float)(s * Mi[i][1] * 8.0);
        p[i*4+2] = (float)(s * Mi[i][2]);
        p[i*4+3] = (float)(s * tv[i] + 15.5);
    }
    p[12] = (float)nearv;
    p[13] = (float)step;
}

__global__ void setup_params(const float* __restrict__ RT, const float* __restrict__ Km,
                             const int* __restrict__ tidx, float* __restrict__ params) {
    int bt = threadIdx.x;
    if (bt < BT) setup_one(bt, RT, Km, tidx, params);
}

// ---------------------------------------------------------------------------
// Fused: convert+transpose (B,C,32^3) f32 -> (B,32^3,C) bf16 (RNE), plus the
// last block computes the per-view params. Grid: BB*512 + 1 blocks x 256 thr.
// ---------------------------------------------------------------------------
__global__ __launch_bounds__(256) void prep_kernel(const float* __restrict__ vol,
                                                   ushort* __restrict__ volTb,
                                                   const float* __restrict__ RT,
                                                   const float* __restrict__ Km,
                                                   const int* __restrict__ tidx,
                                                   float* __restrict__ params) {
    if (blockIdx.x == BB * 512) {
        int bt = threadIdx.x;
        if (bt < BT) setup_one(bt, RT, Km, tidx, params);
        return;
    }
    __shared__ ushort tl[64 * 66];     // stride 66 -> conflict-free both phases
    int b    = blockIdx.x >> 9;        // 512 tiles per batch
    int tile = blockIdx.x & 511;
    size_t zyx0 = (size_t)tile << 6;
    int l  = threadIdx.x & 63;
    int gq = threadIdx.x >> 6;         // 0..3
    #pragma unroll
    for (int k = 0; k < 16; ++k) {
        int c = (gq << 4) + k;
        float v = vol[(((size_t)(b * 64 + c)) << 15) + zyx0 + l];
        uint32_t u = __float_as_uint(v);
        tl[l * 66 + c] = (ushort)((u + 0x7fffu + ((u >> 16) & 1u)) >> 16);  // RNE
    }
    __syncthreads();
    #pragma unroll
    for (int k = 0; k < 16; ++k) {
        int zy = (gq << 4) + k;
        volTb[((size_t)b << 21) + ((zyx0 + zy) << 6) + l] = tl[zy * 66 + l];
    }
}

// ---------------------------------------------------------------------------
// Main sampler on bf16 channel-last volume.
// Block = 512 threads (8 waves) covering 64 sample points (2 h-rows).
// Wave lane = point*8 + octet: corner load = uint4 (8 bf16 channels, 16B);
// 8 lanes x 16B = one dense 128B record; 8 points/wave -> 1KB per load instr.
// Fast path: if the whole block is outside the volume (common with these
// random poses), skip the LDS round-trip and store float4 zeros directly.
// ---------------------------------------------------------------------------
__global__ __launch_bounds__(512) void sample_bf16(const ushort* __restrict__ volTb,
                                                   const float* __restrict__ params,
                                                   float* __restrict__ feats,
                                                   float* __restrict__ depthv) {
    __shared__ float lds[64 * 65];
    int t   = threadIdx.x;
    int blk = blockIdx.x;              // bt*(DD*16) + d*16 + hp
    int hp = blk & 15;
    int t2 = blk >> 4;
    int d  = t2 % DD;
    int bt = t2 / DD;
    int b  = bt >> 3;                  // TN = 8

    const float* p = params + bt * 16;
    float depth = fmaf(p[13], (float)d, p[12]);

    int lane = t & 63;
    int wv   = t >> 6;                 // 0..7
    int pp   = lane >> 3;              // 0..7 point within wave
    int q    = lane & 7;               // channel octet
    int pidx = (wv << 3) | pp;         // 0..63
    int w    = pidx & 31;
    int h0   = hp << 1;
    int h    = h0 | (pidx >> 5);

    float fw = (float)w, fh = (float)h;
    float cx = fmaf(depth, fmaf(p[0], fw, fmaf(p[1], fh, p[2])),  p[3]);
    float cy = fmaf(depth, fmaf(p[4], fw, fmaf(p[5], fh, p[6])),  p[7]);
    float cz = fmaf(depth, fmaf(p[8], fw, fmaf(p[9], fh, p[10])), p[11]);

    bool inside = (cx > -1.f) && (cx < 32.f) && (cy > -1.f) && (cy < 32.f)
               && (cz > -1.f) && (cz < 32.f);

    float acc[8] = {0.f, 0.f, 0.f, 0.f, 0.f, 0.f, 0.f, 0.f};
    if (inside) {
        float xf = floorf(cx), yf = floorf(cy), zf = floorf(cz);
        int x0 = (int)xf, y0 = (int)yf, z0 = (int)zf;
        float xd = cx - xf, yd = cy - yf, zd = cz - zf;
        int x0c = max(x0, 0), x1c = min(x0 + 1, 31);
        int y0c = max(y0, 0), y1c = min(y0 + 1, 31);
        int z0c = max(z0, 0), z1c = min(z0 + 1, 31);
        float wx0 = (x0     >= 0)  ? 1.f - xd : 0.f;
        float wx1 = (x0 + 1 <= 31) ? xd       : 0.f;
        float wy0 = (y0     >= 0)  ? 1.f - yd : 0.f;
        float wy1 = (y0 + 1 <= 31) ? yd       : 0.f;
        float wz0 = (z0     >= 0)  ? 1.f - zd : 0.f;
        float wz1 = (z0 + 1 <= 31) ? zd       : 0.f;

        const ushort* vb = volTb + ((size_t)b << 21) + (q << 3);
        #define CORNER(zc, yc, xc, WGT) do {                                         \
            const uint4 v = *reinterpret_cast<const uint4*>(                          \
                vb + ((((size_t)(zc) * 32 + (yc)) * 32 + (xc)) << 6));                \
            float wg = (WGT);                                                         \
            acc[0] = fmaf(wg, __uint_as_float(v.x << 16),          acc[0]);           \
            acc[1] = fmaf(wg, __uint_as_float(v.x & 0xffff0000u),  acc[1]);           \
            acc[2] = fmaf(wg, __uint_as_float(v.y << 16),          acc[2]);           \
            acc[3] = fmaf(wg, __uint_as_float(v.y & 0xffff0000u),  acc[3]);           \
            acc[4] = fmaf(wg, __uint_as_float(v.z << 16),          acc[4]);           \
            acc[5] = fmaf(wg, __uint_as_float(v.z & 0xffff0000u),  acc[5]);           \
            acc[6] = fmaf(wg, __uint_as_float(v.w << 16),          acc[6]);           \
            acc[7] = fmaf(wg, __uint_as_float(v.w & 0xffff0000u),  acc[7]);           \
        } while (0)
        CORNER(z0c, y0c, x0c, wz0 * wy0 * wx0);
        CORNER(z0c, y0c, x1c, wz0 * wy0 * wx1);
        CORNER(z0c, y1c, x0c, wz0 * wy1 * wx0);
        CORNER(z0c, y1c, x1c, wz0 * wy1 * wx1);
        CORNER(z1c, y0c, x0c, wz1 * wy0 * wx0);
        CORNER(z1c, y0c, x1c, wz1 * wy0 * wx1);
        CORNER(z1c, y1c, x0c, wz1 * wy1 * wx0);
        CORNER(z1c, y1c, x1c, wz1 * wy1 * wx1);
        #undef CORNER
    }

    int allout = __syncthreads_and((int)(!inside));
    if (allout) {
        // whole block outside: store zeros directly, float4 per iteration
        const float4 z4 = {0.f, 0.f, 0.f, 0.f};
        #pragma unroll
        for (int i = 0; i < 2; ++i) {
            int idx = (i << 9) | t;
            int c   = idx >> 4;
            int p4  = idx & 15;
            size_t o = (((size_t)(bt * CC + c) * DD + d) << 10) + (h0 << 5) + (p4 << 2);
            *reinterpret_cast<float4*>(&feats[o]) = z4;
        }
    } else {
        // stage [pt][c]: pad 65 -> banks (65*pt+c)%32, 2-way (free)
        #pragma unroll
        for (int j = 0; j < 8; ++j)
            lds[pidx * 65 + (q << 3) + j] = acc[j];
        __syncthreads();
        // coalesced channel-major write, float4 along pt
        #pragma unroll
        for (int i = 0; i < 2; ++i) {
            int idx = (i << 9) | t;
            int c   = idx >> 4;
            int p4  = idx & 15;
            float4 v;
            v.x = lds[(p4 * 4 + 0) * 65 + c];
            v.y = lds[(p4 * 4 + 1) * 65 + c];
            v.z = lds[(p4 * 4 + 2) * 65 + c];
            v.w = lds[(p4 * 4 + 3) * 65 + c];
            size_t o = (((size_t)(bt * CC + c) * DD + d) << 10) + (h0 << 5) + (p4 << 2);
            *reinterpret_cast<float4*>(&feats[o]) = v;
        }
    }
    if (t < 16) {
        float4 d4 = {depth, depth, depth, depth};
        float* dp = depthv + (((size_t)bt * DD + d) << 10) + (h0 << 5);
        reinterpret_cast<float4*>(dp)[t] = d4;
    }
}

// ---------------------------------------------------------------------------
// Fallback on original layout (only if workspace too small for volTb).
// ---------------------------------------------------------------------------
__global__ __launch_bounds__(512) void sample_fallback(const float* __restrict__ vol,
                                                       const float* __restrict__ params,
                                                       float* __restrict__ feats,
                                                       float* __restrict__ depthv) {
    int w  = threadIdx.x;
    int ty = threadIdx.y;
    int blk = blockIdx.x;
    int h  = blk & 31;
    int t2 = blk >> 5;
    int d  = t2 % DD;
    int bt = t2 / DD;
    int b  = bt >> 3;

    const float* p = params + bt * 16;
    float depth = fmaf(p[13], (float)d, p[12]);
    float fw = (float)w, fh = (float)h;
    float cx = fmaf(depth, fmaf(p[0], fw, fmaf(p[1], fh, p[2])),  p[3]);
    float cy = fmaf(depth, fmaf(p[4], fw, fmaf(p[5], fh, p[6])),  p[7]);
    float cz = fmaf(depth, fmaf(p[8], fw, fmaf(p[9], fh, p[10])), p[11]);

    float accs[4] = {0.f, 0.f, 0.f, 0.f};
    bool inside = (cx > -1.f) && (cx < 32.f) && (cy > -1.f) && (cy < 32.f)
               && (cz > -1.f) && (cz < 32.f);
    if (inside) {
        float xf = floorf(cx), yf = floorf(cy), zf = floorf(cz);
        int x0 = (int)xf, y0 = (int)yf, z0 = (int)zf;
        float xd = cx - xf, yd = cy - yf, zd = cz - zf;
        int x0c = max(x0, 0), x1c = min(x0 + 1, 31);
        int y0c = max(y0, 0), y1c = min(y0 + 1, 31);
        int z0c = max(z0, 0), z1c = min(z0 + 1, 31);
        float wx0 = (x0     >= 0)  ? 1.f - xd : 0.f;
        float wx1 = (x0 + 1 <= 31) ? xd       : 0.f;
        float wy0 = (y0     >= 0)  ? 1.f - yd : 0.f;
        float wy1 = (y0 + 1 <= 31) ? yd       : 0.f;
        float wz0 = (z0     >= 0)  ? 1.f - zd : 0.f;
        float wz1 = (z0 + 1 <= 31) ? zd       : 0.f;
        int o000 = ((z0c * 32) + y0c) * 32 + x0c;
        int o001 = ((z0c * 32) + y0c) * 32 + x1c;
        int o010 = ((z0c * 32) + y1c) * 32 + x0c;
        int o011 = ((z0c * 32) + y1c) * 32 + x1c;
        int o100 = ((z1c * 32) + y0c) * 32 + x0c;
        int o101 = ((z1c * 32) + y0c) * 32 + x1c;
        int o110 = ((z1c * 32) + y1c) * 32 + x0c;
        int o111 = ((z1c * 32) + y1c) * 32 + x1c;
        float w000 = wz0*wy0*wx0, w001 = wz0*wy0*wx1, w010 = wz0*wy1*wx0, w011 = wz0*wy1*wx1;
        float w100 = wz1*wy0*wx0, w101 = wz1*wy0*wx1, w110 = wz1*wy1*wx0, w111 = wz1*wy1*wx1;
        #pragma unroll
        for (int k = 0; k < 4; ++k) {
            const float* vc = vol + (size_t)(b * CC + (ty << 2) + k) * V3;
            float a = 0.f;
            a = fmaf(w000, vc[o000], a); a = fmaf(w001, vc[o001], a);
            a = fmaf(w010, vc[o010], a); a = fmaf(w011, vc[o011], a);
            a = fmaf(w100, vc[o100], a); a = fmaf(w101, vc[o101], a);
            a = fmaf(w110, vc[o110], a); a = fmaf(w111, vc[o111], a);
            accs[k] = a;
        }
    }
    const size_t CHs = (size_t)DD * HH * WW;
    size_t o = (((size_t)bt * CC + (ty << 2)) * DD + d) * (HH * WW) + h * WW + w;
    feats[o]           = accs[0];
    feats[o + CHs]     = accs[1];
    feats[o + 2 * CHs] = accs[2];
    feats[o + 3 * CHs] = accs[3];
    if (ty == 0)
        depthv[((size_t)bt * DD + d) * (HH * WW) + h * WW + w] = depth;
}

extern "C" void kernel_launch(void* const* d_in, const int* in_sizes, int n_in,
                              void* d_out, int out_size, void* d_ws, size_t ws_size,
                              hipStream_t stream) {
    const float* vol  = (const float*)d_in[0];
    const float* RT   = (const float*)d_in[1];
    const float* Km   = (const float*)d_in[2];
    const int*   tidx = (const int*)d_in[3];

    float* feats  = (float*)d_out;
    float* depthv = feats + (size_t)BT * CC * DD * HH * WW;

    float*  params = (float*)d_ws;
    ushort* volTb  = (ushort*)((char*)d_ws + 4096);
    const size_t volTb_bytes = (size_t)BB * CC * V3 * sizeof(ushort);   // 8 MB
    bool use_cl = ws_size >= 4096 + volTb_bytes;

    if (use_cl) {
        prep_kernel<<<BB * 512 + 1, 256, 0, stream>>>(vol, volTb, RT, Km, tidx, params);
        sample_bf16<<<BT * DD * (HH / 2), 512, 0, stream>>>(volTb, params, feats, depthv);
    } else {
        setup_params<<<1, 64, 0, stream>>>(RT, Km, tidx, params);
        sample_fallback<<<BT * DD * HH, dim3(32, 16, 1), 0, stream>>>(vol, params, feats, depthv);
    }
}

// Round 6
// 212.726 us; speedup vs baseline: 1.1180x; 1.0088x over previous
//
#include <hip/hip_runtime.h>
#include <cstdint>

#define BB   2
#define NN   16
#define TNN  8
#define BT   16
#define CC   64
#define VV   32
#define V3   (VV*VV*VV)
#define DD   48
#define HH   32
#define WW   32
#define FVL_ 0.86603
#define DCH  4              /* depth chunks per (bt,hp); 12 d-slices each */

// ---------------------------------------------------------------------------
// Per-view projection coefficients (double precision).
// coord_i = depth*(A_i*w + B_i*h + C_i) + D_i  (align_corners mapping folded:
// coord = 31*xyz + 15.5).  params[bt*16+{0..11}] = rows; [12]=near; [13]=step
// ---------------------------------------------------------------------------
__device__ void setup_one(int bt, const float* __restrict__ RT,
                          const float* __restrict__ Km,
                          const int* __restrict__ tidx, float* __restrict__ params) {
    int b = bt / TNN, j = bt % TNN;
    int n = tidx[b * TNN + j];
    const float* pose = RT + (size_t)(b * NN + n) * 12;   // 3x4
    const float* K    = Km + (size_t)(b * NN + n) * 16;   // 4x4

    double T0 = pose[3], T1 = pose[7], T2 = pose[11];
    double cp0 = -((double)pose[0] * T0 + (double)pose[4] * T1 + (double)pose[8]  * T2);
    double cp1 = -((double)pose[1] * T0 + (double)pose[5] * T1 + (double)pose[9]  * T2);
    double cp2 = -((double)pose[2] * T0 + (double)pose[6] * T1 + (double)pose[10] * T2);
    double dist = sqrt(cp0*cp0 + cp1*cp1 + cp2*cp2);
    double nearv = dist - FVL_;
    double step  = 2.0 * FVL_ / (DD - 1);

    double A[3][3], bv[3];
    #pragma unroll
    for (int i = 0; i < 3; ++i) {
        #pragma unroll
        for (int jj = 0; jj < 3; ++jj)
            A[i][jj] = (double)K[i*4+0]*pose[0*4+jj] + (double)K[i*4+1]*pose[1*4+jj]
                     + (double)K[i*4+2]*pose[2*4+jj];
        bv[i] = (double)K[i*4+0]*pose[3] + (double)K[i*4+1]*pose[7] + (double)K[i*4+2]*pose[11];
    }
    double c00 =  A[1][1]*A[2][2] - A[1][2]*A[2][1];
    double c01 =  A[1][2]*A[2][0] - A[1][0]*A[2][2];
    double c02 =  A[1][0]*A[2][1] - A[1][1]*A[2][0];
    double det = A[0][0]*c00 + A[0][1]*c01 + A[0][2]*c02;
    double Mi[3][3];
    Mi[0][0] = c00 / det;
    Mi[0][1] = (A[0][2]*A[2][1] - A[0][1]*A[2][2]) / det;
    Mi[0][2] = (A[0][1]*A[1][2] - A[0][2]*A[1][1]) / det;
    Mi[1][0] = c01 / det;
    Mi[1][1] = (A[0][0]*A[2][2] - A[0][2]*A[2][0]) / det;
    Mi[1][2] = (A[0][2]*A[1][0] - A[0][0]*A[1][2]) / det;
    Mi[2][0] = c02 / det;
    Mi[2][1] = (A[0][1]*A[2][0] - A[0][0]*A[2][1]) / det;
    Mi[2][2] = (A[0][0]*A[1][1] - A[0][1]*A[1][0]) / det;
    double tv[3];
    #pragma unroll
    for (int i = 0; i < 3; ++i)
        tv[i] = -(Mi[i][0]*bv[0] + Mi[i][1]*bv[1] + Mi[i][2]*bv[2]);

    const double s = 31.0;  // 0.5*(V-1)/SVL
    float* p = params + bt * 16;
    #pragma unroll
    for (int i = 0; i < 3; ++i) {
        p[i*4+0] = (float)(s * Mi[i][0] * 8.0);
        p[i*4+1] = (float)(s * Mi[i][1] * 8.0);
        p[i*4+2] = (float)(s * Mi[i][2]);
        p[i*4+3] = (float)(s * tv[i] + 15.5);
    }
    p[12] = (float)nearv;
    p[13] = (float)step;
}

__global__ void setup_params(const float* __restrict__ RT, const float* __restrict__ Km,
                             const int* __restrict__ tidx, float* __restrict__ params) {
    int bt = threadIdx.x;
    if (bt < BT) setup_one(bt, RT, Km, tidx, params);
}

// ---------------------------------------------------------------------------
// Fused: convert+transpose (B,C,32^3) f32 -> (B,32^3,C) bf16 (RNE), plus the
// last block computes the per-view params. Grid: BB*512 + 1 blocks x 256 thr.
// ---------------------------------------------------------------------------
__global__ __launch_bounds__(256) void prep_kernel(const float* __restrict__ vol,
                                                   ushort* __restrict__ volTb,
                                                   const float* __restrict__ RT,
                                                   const float* __restrict__ Km,
                                                   const int* __restrict__ tidx,
                                                   float* __restrict__ params) {
    if (blockIdx.x == BB * 512) {
        int bt = threadIdx.x;
        if (bt < BT) setup_one(bt, RT, Km, tidx, params);
        return;
    }
    __shared__ ushort tl[64 * 66];     // stride 66 -> conflict-free both phases
    int b    = blockIdx.x >> 9;        // 512 tiles per batch
    int tile = blockIdx.x & 511;
    size_t zyx0 = (size_t)tile << 6;
    int l  = threadIdx.x & 63;
    int gq = threadIdx.x >> 6;         // 0..3
    #pragma unroll
    for (int k = 0; k < 16; ++k) {
        int c = (gq << 4) + k;
        float v = vol[(((size_t)(b * 64 + c)) << 15) + zyx0 + l];
        uint32_t u = __float_as_uint(v);
        tl[l * 66 + c] = (ushort)((u + 0x7fffu + ((u >> 16) & 1u)) >> 16);  // RNE
    }
    __syncthreads();
    #pragma unroll
    for (int k = 0; k < 16; ++k) {
        int zy = (gq << 4) + k;
        volTb[((size_t)b << 21) + ((zyx0 + zy) << 6) + l] = tl[zy * 66 + l];
    }
}

// ---------------------------------------------------------------------------
// Main sampler on bf16 channel-last volume, depth-looped.
// Grid = BT*16*DCH blocks (1024 = 4/CU) x 512 threads; each block owns
// (bt, h-pair) x 12 consecutive depth slices -> per-block setup amortized,
// streaming float4 stores, ray-adjacent corner records reuse L1/L2.
// Wave lane = point*8 + channel-octet: corner load = uint4 (8 bf16 ch, 16B);
// coords recomputed per-d with the exact fmaf chain (bit-identical to the
// per-block version -> matches reference rounding).
// ---------------------------------------------------------------------------
__global__ __launch_bounds__(512) void sample_bf16(const ushort* __restrict__ volTb,
                                                   const float* __restrict__ params,
                                                   float* __restrict__ feats,
                                                   float* __restrict__ depthv) {
    __shared__ float lds[64 * 65];
    int t   = threadIdx.x;
    int blk = blockIdx.x;              // ((bt*DCH + dc)*16) + hp
    int hp = blk & 15;
    int r  = blk >> 4;
    int dc = r & (DCH - 1);
    int bt = r / DCH;
    int b  = bt >> 3;                  // TN = 8

    const float* p = params + bt * 16;

    int lane = t & 63;
    int wv   = t >> 6;                 // 0..7
    int pp   = lane >> 3;              // 0..7 point within wave
    int q    = lane & 7;               // channel octet
    int pidx = (wv << 3) | pp;         // 0..63
    int w    = pidx & 31;
    int h0   = hp << 1;
    int h    = h0 | (pidx >> 5);

    float fw = (float)w, fh = (float)h;
    float Gx = fmaf(p[0], fw, fmaf(p[1], fh, p[2]));
    float Gy = fmaf(p[4], fw, fmaf(p[5], fh, p[6]));
    float Gz = fmaf(p[8], fw, fmaf(p[9], fh, p[10]));
    float px3 = p[3], py3 = p[7], pz3 = p[11];
    float nearv = p[12], step = p[13];

    const ushort* vb = volTb + ((size_t)b << 21) + (q << 3);

    // store-role constants (thread -> (c, p4) for both write phases)
    int cA  = t >> 4;                  // 0..31   (idx = t)
    int p4A = t & 15;
    int cB  = cA + 32;                 // idx = 512 + t
    size_t oBaseA = ((size_t)(bt * CC + cA) * DD) << 10;
    size_t oBaseB = ((size_t)(bt * CC + cB) * DD) << 10;
    size_t oTail  = (size_t)(h0 << 5);
    size_t dBase  = ((size_t)bt * DD) << 10;

    const int d0 = dc * (DD / DCH);
    for (int dd = 0; dd < DD / DCH; ++dd) {
        int d = d0 + dd;
        float depth = fmaf(step, (float)d, nearv);
        float cx = fmaf(depth, Gx, px3);
        float cy = fmaf(depth, Gy, py3);
        float cz = fmaf(depth, Gz, pz3);

        bool inside = (cx > -1.f) && (cx < 32.f) && (cy > -1.f) && (cy < 32.f)
                   && (cz > -1.f) && (cz < 32.f);

        float acc[8] = {0.f, 0.f, 0.f, 0.f, 0.f, 0.f, 0.f, 0.f};
        if (inside) {
            float xf = floorf(cx), yf = floorf(cy), zf = floorf(cz);
            int x0 = (int)xf, y0 = (int)yf, z0 = (int)zf;
            float xd = cx - xf, yd = cy - yf, zd = cz - zf;
            int x0c = max(x0, 0), x1c = min(x0 + 1, 31);
            int y0c = max(y0, 0), y1c = min(y0 + 1, 31);
            int z0c = max(z0, 0), z1c = min(z0 + 1, 31);
            float wx0 = (x0     >= 0)  ? 1.f - xd : 0.f;
            float wx1 = (x0 + 1 <= 31) ? xd       : 0.f;
            float wy0 = (y0     >= 0)  ? 1.f - yd : 0.f;
            float wy1 = (y0 + 1 <= 31) ? yd       : 0.f;
            float wz0 = (z0     >= 0)  ? 1.f - zd : 0.f;
            float wz1 = (z0 + 1 <= 31) ? zd       : 0.f;

            #define CORNER(zc, yc, xc, WGT) do {                                     \
                const uint4 v = *reinterpret_cast<const uint4*>(                      \
                    vb + ((((size_t)(zc) * 32 + (yc)) * 32 + (xc)) << 6));            \
                float wg = (WGT);                                                     \
                acc[0] = fmaf(wg, __uint_as_float(v.x << 16),          acc[0]);       \
                acc[1] = fmaf(wg, __uint_as_float(v.x & 0xffff0000u),  acc[1]);       \
                acc[2] = fmaf(wg, __uint_as_float(v.y << 16),          acc[2]);       \
                acc[3] = fmaf(wg, __uint_as_float(v.y & 0xffff0000u),  acc[3]);       \
                acc[4] = fmaf(wg, __uint_as_float(v.z << 16),          acc[4]);       \
                acc[5] = fmaf(wg, __uint_as_float(v.z & 0xffff0000u),  acc[5]);       \
                acc[6] = fmaf(wg, __uint_as_float(v.w << 16),          acc[6]);       \
                acc[7] = fmaf(wg, __uint_as_float(v.w & 0xffff0000u),  acc[7]);       \
            } while (0)
            CORNER(z0c, y0c, x0c, wz0 * wy0 * wx0);
            CORNER(z0c, y0c, x1c, wz0 * wy0 * wx1);
            CORNER(z0c, y1c, x0c, wz0 * wy1 * wx0);
            CORNER(z0c, y1c, x1c, wz0 * wy1 * wx1);
            CORNER(z1c, y0c, x0c, wz1 * wy0 * wx0);
            CORNER(z1c, y0c, x1c, wz1 * wy0 * wx1);
            CORNER(z1c, y1c, x0c, wz1 * wy1 * wx0);
            CORNER(z1c, y1c, x1c, wz1 * wy1 * wx1);
            #undef CORNER
        }

        // full barrier + block-wide vote (also protects LDS reuse across d)
        int allout = __syncthreads_and((int)(!inside));
        size_t dOff = ((size_t)d) << 10;
        if (allout) {
            const float4 z4 = {0.f, 0.f, 0.f, 0.f};
            *reinterpret_cast<float4*>(&feats[oBaseA + dOff + oTail + (p4A << 2)]) = z4;
            *reinterpret_cast<float4*>(&feats[oBaseB + dOff + oTail + (p4A << 2)]) = z4;
        } else {
            #pragma unroll
            for (int j = 0; j < 8; ++j)
                lds[pidx * 65 + (q << 3) + j] = acc[j];
            __syncthreads();
            float4 v0, v1;
            v0.x = lds[(p4A * 4 + 0) * 65 + cA];
            v0.y = lds[(p4A * 4 + 1) * 65 + cA];
            v0.z = lds[(p4A * 4 + 2) * 65 + cA];
            v0.w = lds[(p4A * 4 + 3) * 65 + cA];
            v1.x = lds[(p4A * 4 + 0) * 65 + cB];
            v1.y = lds[(p4A * 4 + 1) * 65 + cB];
            v1.z = lds[(p4A * 4 + 2) * 65 + cB];
            v1.w = lds[(p4A * 4 + 3) * 65 + cB];
            *reinterpret_cast<float4*>(&feats[oBaseA + dOff + oTail + (p4A << 2)]) = v0;
            *reinterpret_cast<float4*>(&feats[oBaseB + dOff + oTail + (p4A << 2)]) = v1;
        }
        if (t < 16) {
            float depthb = fmaf(step, (float)d, nearv);
            float4 d4 = {depthb, depthb, depthb, depthb};
            reinterpret_cast<float4*>(&depthv[dBase + dOff + oTail])[t] = d4;
        }
    }
}

// ---------------------------------------------------------------------------
// Fallback on original layout (only if workspace too small for volTb).
// ---------------------------------------------------------------------------
__global__ __launch_bounds__(512) void sample_fallback(const float* __restrict__ vol,
                                                       const float* __restrict__ params,
                                                       float* __restrict__ feats,
                                                       float* __restrict__ depthv) {
    int w  = threadIdx.x;
    int ty = threadIdx.y;
    int blk = blockIdx.x;
    int h  = blk & 31;
    int t2 = blk >> 5;
    int d  = t2 % DD;
    int bt = t2 / DD;
    int b  = bt >> 3;

    const float* p = params + bt * 16;
    float depth = fmaf(p[13], (float)d, p[12]);
    float fw = (float)w, fh = (float)h;
    float cx = fmaf(depth, fmaf(p[0], fw, fmaf(p[1], fh, p[2])),  p[3]);
    float cy = fmaf(depth, fmaf(p[4], fw, fmaf(p[5], fh, p[6])),  p[7]);
    float cz = fmaf(depth, fmaf(p[8], fw, fmaf(p[9], fh, p[10])), p[11]);

    float accs[4] = {0.f, 0.f, 0.f, 0.f};
    bool inside = (cx > -1.f) && (cx < 32.f) && (cy > -1.f) && (cy < 32.f)
               && (cz > -1.f) && (cz < 32.f);
    if (inside) {
        float xf = floorf(cx), yf = floorf(cy), zf = floorf(cz);
        int x0 = (int)xf, y0 = (int)yf, z0 = (int)zf;
        float xd = cx - xf, yd = cy - yf, zd = cz - zf;
        int x0c = max(x0, 0), x1c = min(x0 + 1, 31);
        int y0c = max(y0, 0), y1c = min(y0 + 1, 31);
        int z0c = max(z0, 0), z1c = min(z0 + 1, 31);
        float wx0 = (x0     >= 0)  ? 1.f - xd : 0.f;
        float wx1 = (x0 + 1 <= 31) ? xd       : 0.f;
        float wy0 = (y0     >= 0)  ? 1.f - yd : 0.f;
        float wy1 = (y0 + 1 <= 31) ? yd       : 0.f;
        float wz0 = (z0     >= 0)  ? 1.f - zd : 0.f;
        float wz1 = (z0 + 1 <= 31) ? zd       : 0.f;
        int o000 = ((z0c * 32) + y0c) * 32 + x0c;
        int o001 = ((z0c * 32) + y0c) * 32 + x1c;
        int o010 = ((z0c * 32) + y1c) * 32 + x0c;
        int o011 = ((z0c * 32) + y1c) * 32 + x1c;
        int o100 = ((z1c * 32) + y0c) * 32 + x0c;
        int o101 = ((z1c * 32) + y0c) * 32 + x1c;
        int o110 = ((z1c * 32) + y1c) * 32 + x0c;
        int o111 = ((z1c * 32) + y1c) * 32 + x1c;
        float w000 = wz0*wy0*wx0, w001 = wz0*wy0*wx1, w010 = wz0*wy1*wx0, w011 = wz0*wy1*wx1;
        float w100 = wz1*wy0*wx0, w101 = wz1*wy0*wx1, w110 = wz1*wy1*wx0, w111 = wz1*wy1*wx1;
        #pragma unroll
        for (int k = 0; k < 4; ++k) {
            const float* vc = vol + (size_t)(b * CC + (ty << 2) + k) * V3;
            float a = 0.f;
            a = fmaf(w000, vc[o000], a); a = fmaf(w001, vc[o001], a);
            a = fmaf(w010, vc[o010], a); a = fmaf(w011, vc[o011], a);
            a = fmaf(w100, vc[o100], a); a = fmaf(w101, vc[o101], a);
            a = fmaf(w110, vc[o110], a); a = fmaf(w111, vc[o111], a);
            accs[k] = a;
        }
    }
    const size_t CHs = (size_t)DD * HH * WW;
    size_t o = (((size_t)bt * CC + (ty << 2)) * DD + d) * (HH * WW) + h * WW + w;
    feats[o]           = accs[0];
    feats[o + CHs]     = accs[1];
    feats[o + 2 * CHs] = accs[2];
    feats[o + 3 * CHs] = accs[3];
    if (ty == 0)
        depthv[((size_t)bt * DD + d) * (HH * WW) + h * WW + w] = depth;
}

extern "C" void kernel_launch(void* const* d_in, const int* in_sizes, int n_in,
                              void* d_out, int out_size, void* d_ws, size_t ws_size,
                              hipStream_t stream) {
    const float* vol  = (const float*)d_in[0];
    const float* RT   = (const float*)d_in[1];
    const float* Km   = (const float*)d_in[2];
    const int*   tidx = (const int*)d_in[3];

    float* feats  = (float*)d_out;
    float* depthv = feats + (size_t)BT * CC * DD * HH * WW;

    float*  params = (float*)d_ws;
    ushort* volTb  = (ushort*)((char*)d_ws + 4096);
    const size_t volTb_bytes = (size_t)BB * CC * V3 * sizeof(ushort);   // 8 MB
    bool use_cl = ws_size >= 4096 + volTb_bytes;

    if (use_cl) {
        prep_kernel<<<BB * 512 + 1, 256, 0, stream>>>(vol, volTb, RT, Km, tidx, params);
        sample_bf16<<<BT * 16 * DCH, 512, 0, stream>>>(volTb, params, feats, depthv);
    } else {
        setup_params<<<1, 64, 0, stream>>>(RT, Km, tidx, params);
        sample_fallback<<<BT * DD * HH, dim3(32, 16, 1), 0, stream>>>(vol, params, feats, depthv);
    }
}